// Round 10
// baseline (148.507 us; speedup 1.0000x reference)
//
#include <hip/hip_runtime.h>
#include <cstdint>

#define R_SPHEREf 3.0f
#define NEARf 0.0f
#define FARf 100.0f
#define SECANT_STEPS 4
#define EPSf 1e-4f
#define R0f 1.0f
#define Hh 64
#define Lc 4
#define Sn 64

// w2*tanh(x) = w2 - 2*w2*r,  r = 1/(exp2(C*x)+1),  C = 2*log2(e) folded into
// the per-ray linearization (A2,B2); -2*w2 = m2w2; Sum(w2)+b2+R0 = sbase.
// R10 change vs R5 (best, 70us): coefficients are wave-uniform, so they are
// moved to SGPRs via v_readlane (192 readlanes once per wave) and the main
// lane=sample loop uses SGPR-broadcast operands — ZERO ds_read in the hot
// loop. R5 was DS-pipe-bound (~86% of the per-CU LDS pipe: 64 broadcast
// ds_read_b128 + ~60 shfl/ballot per wave). Phase-A numerics byte-identical
// to R5 (single acc, h ascending): measured absmax 4.9e-4.
#define C_HI 2.88539004325866699f
#define C_LO 3.8519227871e-08f

__device__ __forceinline__ float readlane_f(float v, int l) {
    return __int_as_float(__builtin_amdgcn_readlane(__float_as_int(v), l));
}

__global__ __launch_bounds__(256) void manifold_render_kernel(
    const float* __restrict__ rays_o, const float* __restrict__ rays_d,
    const float* __restrict__ levels, const float* __restrict__ W1,
    const float* __restrict__ b1, const float* __restrict__ W2,
    const float* __restrict__ b2, float* __restrict__ out, int N)
{
    // per-wave {A2_h, B2_h, -2*w2_h, w2sum} quads (secant phase only)
    __shared__ float4 abq[4][Hh];

    const int tid = threadIdx.x;
    const int wave = tid >> 6;
    const int lane = tid & 63;
    const int r = blockIdx.x * 4 + wave;
    const bool ray_ok = (r < N);

    const float b2v = b2[0];
    float lvl[Lc];
#pragma unroll
    for (int j = 0; j < Lc; ++j) lvl[j] = levels[j];

    float ox = 0.f, oy = 0.f, oz = 0.f, dx = 0.f, dy = 0.f, dz = 1.f;
    if (ray_ok) {
        ox = rays_o[3 * r]; oy = rays_o[3 * r + 1]; oz = rays_o[3 * r + 2];
        dx = rays_d[3 * r]; dy = rays_d[3 * r + 1]; dz = rays_d[3 * r + 2];
    }

    // per-ray linearization, lane h = lane; fold C into A,B; fold -2 into w2
    float A2, B2, m2w2;
    {
        const float w1x = W1[lane], w1y = W1[Hh + lane], w1z = W1[2 * Hh + lane];
        const float w2lane = W2[lane];
        const float Ah = __builtin_fmaf(oz, w1z, __builtin_fmaf(oy, w1y,
                         __builtin_fmaf(ox, w1x, b1[lane])));
        const float Bh = __builtin_fmaf(dz, w1z, __builtin_fmaf(dy, w1y, dx * w1x));
        A2 = __builtin_fmaf(Ah, C_LO, Ah * C_HI);
        B2 = __builtin_fmaf(Bh, C_LO, Bh * C_HI);
        m2w2 = -2.0f * w2lane;
        // Sum(w2) across wave (ray-independent): butterfly
        float w2sum = w2lane;
#pragma unroll
        for (int m = 1; m < 64; m <<= 1) w2sum += __shfl_xor(w2sum, m);
        abq[wave][lane] = make_float4(A2, B2, m2w2, w2sum);
    }
    __syncthreads();
    const float sbase = abq[wave][0].w + b2v + R0f;
    if (!ray_ok) return;

    // sphere bounds
    const float bq = ox * dx + oy * dy + oz * dz;
    const float cq = ox * ox + oy * oy + oz * oz - R_SPHEREf * R_SPHEREf;
    const float disc = bq * bq - cq;
    const bool hit = disc > 0.0f;
    const float sq = sqrtf(hit ? disc : 1.0f);
    const float d_near = fmaxf(-bq - sq, NEARf);
    const float d_far  = fminf(-bq + sq, FARf);
    const bool mask_bound = hit && (d_near < d_far);

    // ---- sampling: lane = sample index; coefficients via SGPR broadcast ----
    const float t = (float)lane / (float)(Sn - 1);
    const float dsv = d_near * (1.0f - t) + d_far * t;
    const float x0 = ox + dx * dsv, x1 = oy + dy * dsv, x2 = oz + dz * dsv;
    const float nrm = sqrtf(x0 * x0 + x1 * x1 + x2 * x2);

    float acc = 0.0f;
#pragma unroll
    for (int c = 0; c < 4; ++c) {
        // hoist this chunk's 16 coefficients into wave-uniform regs (SGPRs)
        float sA[16], sB[16], sW[16];
#pragma unroll
        for (int j = 0; j < 16; ++j) {
            const int h = 16 * c + j;
            sA[j] = readlane_f(A2, h);
            sB[j] = readlane_f(B2, h);
            sW[j] = readlane_f(m2w2, h);
        }
#pragma unroll
        for (int j = 0; j < 16; ++j) {
            const float y = __builtin_fmaf(dsv, sB[j], sA[j]);
            const float e = __builtin_amdgcn_exp2f(y);
            const float r1 = __builtin_amdgcn_rcpf(e + 1.0f);
            acc = __builtin_fmaf(sW[j], r1, acc);
        }
    }
    const float scal = (acc + sbase) - nrm;
    const bool valid = nrm < R_SPHEREf;

    // neighbors (back sample of interval at lane j is sample j+1)
    const float scb = __shfl_down(scal, 1);
    const int validn = __shfl_down((int)valid, 1);
    const bool is_int = lane < (Sn - 1);

    // ind_lowest: first-occurrence argmin of sc_b over intervals
    float keyv = is_int ? scb : INFINITY;
    int keyi = lane;
#pragma unroll
    for (int m = 1; m < 64; m <<= 1) {
        float ov = __shfl_xor(keyv, m);
        int oi = __shfl_xor(keyi, m);
        if (ov < keyv || (ov == keyv && oi < keyi)) { keyv = ov; keyi = oi; }
    }
    const int ind_lowest = keyi;

    const bool inint_base = is_int && valid && (validn != 0);

    // per-level interval pick + secant init
    bool mintb[Lc], msec[Lc];
    float dinit[Lc];
    float g_dfs = 0.f, g_dbs = 0.f, g_sfs = 0.f, g_sbs = 0.f, g_dcur = 0.f, g_lr = 0.f;
    const int g = lane >> 4;

#pragma unroll
    for (int lv = 0; lv < Lc; ++lv) {
        const float l = lvl[lv];
        unsigned long long bP = __ballot(is_int && (scb < l));
        unsigned long long bZ = __ballot(is_int && (scb == l));
        unsigned long long bI = __ballot(inint_base && (scal >= l) && (l >= scb));
        int ind_closest = bP ? __builtin_ctzll(bP)
                             : (bZ ? __builtin_ctzll(bZ) : (Sn - 2));
        bool mask_surface = (bI != 0ULL);
        int idx = mask_surface ? ind_closest : ind_lowest;

        float d_front = __shfl(dsv, idx);
        float d_back  = __shfl(dsv, idx + 1);
        float s_front = __shfl(scal, idx);
        float s_back  = __shfl(scal, idx + 1);

        bool mi = (s_front >= l) && (l >= s_back);
        float sd = s_front - s_back;
        bool vd = fabsf(sd) > EPSf;
        bool ms = mi && vd;
        float d_sec = ((l - s_back) * d_front + (s_front - l) * d_back) / (vd ? sd : 1.0f);
        float di = ms ? d_sec : d_back;

        mintb[lv] = mi; msec[lv] = ms; dinit[lv] = di;
        if (g == lv) {
            g_dfs = d_front; g_dbs = d_back; g_sfs = s_front; g_sbs = s_back;
            g_dcur = di; g_lr = l;
        }
    }

    // ---- secant refinement: 16 lanes per level, 4 hidden units per lane ----
    const float4* __restrict__ ab = &abq[wave][0];
    const int sub = lane & 15;
    float4 sq0 = ab[sub], sq1 = ab[sub + 16], sq2 = ab[sub + 32], sq3 = ab[sub + 48];

#pragma unroll
    for (int it = 0; it < SECANT_STEPS; ++it) {
        float mx0 = ox + g_dcur * dx, mx1 = oy + g_dcur * dy, mx2 = oz + g_dcur * dz;
        float mn = sqrtf(mx0 * mx0 + mx1 * mx1 + mx2 * mx2);
        float part;
        {
            float y0 = __builtin_fmaf(g_dcur, sq0.y, sq0.x);
            float y1 = __builtin_fmaf(g_dcur, sq1.y, sq1.x);
            float y2 = __builtin_fmaf(g_dcur, sq2.y, sq2.x);
            float y3 = __builtin_fmaf(g_dcur, sq3.y, sq3.x);
            float r0 = __builtin_amdgcn_rcpf(__builtin_amdgcn_exp2f(y0) + 1.0f);
            float r1 = __builtin_amdgcn_rcpf(__builtin_amdgcn_exp2f(y1) + 1.0f);
            float r2 = __builtin_amdgcn_rcpf(__builtin_amdgcn_exp2f(y2) + 1.0f);
            float r3 = __builtin_amdgcn_rcpf(__builtin_amdgcn_exp2f(y3) + 1.0f);
            part = sq0.z * r0;
            part = __builtin_fmaf(sq1.z, r1, part);
            part = __builtin_fmaf(sq2.z, r2, part);
            part = __builtin_fmaf(sq3.z, r3, part);
        }
#pragma unroll
        for (int m = 1; m < 16; m <<= 1) part += __shfl_xor(part, m, 16);
        float s_mid = (part + sbase) - mn;
        bool mv = mn < R_SPHEREf;
        bool upf = (s_mid > g_lr) && mv;
        bool upb = (s_mid < g_lr) && mv;
        if (upf) { g_dfs = g_dcur; g_sfs = s_mid; }
        if (upb) { g_dbs = g_dcur; g_sbs = s_mid; }
        float sd2 = g_sfs - g_sbs;
        bool ok = fabsf(sd2) > EPSf;
        if (ok) g_dcur = ((g_lr - g_sbs) * g_dfs + (g_sfs - g_lr) * g_dbs) / sd2;
    }

    // gather per-level results onto every lane
    float v0, v1, v2, v3;
    {
        float dc0 = __shfl(g_dcur, 0);
        float dc1 = __shfl(g_dcur, 16);
        float dc2 = __shfl(g_dcur, 32);
        float dc3 = __shfl(g_dcur, 48);
        v0 = msec[0] ? dc0 : dinit[0];
        v1 = msec[1] ? dc1 : dinit[1];
        v2 = msec[2] ? dc2 : dinit[2];
        v3 = msec[3] ? dc3 : dinit[3];
    }
    int m0 = mintb[0], m1 = mintb[1], m2 = mintb[2], m3 = mintb[3];
    int i0 = 0, i1 = 1, i2 = 2, i3 = 3;

    // stable sort of 4 by (value, original index) — 5-comparator network
#define CSWAP(va, ia, ma, vb, ib, mb)                                    \
    { bool sw = (vb < va) || (vb == va && ib < ia);                      \
      if (sw) { float tv = va; va = vb; vb = tv;                         \
                int ti = ia; ia = ib; ib = ti;                           \
                int tm = ma; ma = mb; mb = tm; } }
    CSWAP(v0, i0, m0, v1, i1, m1);
    CSWAP(v2, i2, m2, v3, i3, m3);
    CSWAP(v0, i0, m0, v2, i2, m2);
    CSWAP(v1, i1, m1, v3, i3, m3);
    CSWAP(v1, i1, m1, v2, i2, m2);
#undef CSWAP

    const long long NL = (long long)N * Lc;
    if (lane < Lc) {
        float dv = (lane == 0) ? v0 : (lane == 1) ? v1 : (lane == 2) ? v2 : v3;
        out[(long long)r * Lc + lane] = mask_bound ? dv : 0.0f;
    } else if (lane < 2 * Lc) {
        int k = lane - Lc;
        int mm = (k == 0) ? m0 : (k == 1) ? m1 : (k == 2) ? m2 : m3;
        out[NL + (long long)r * Lc + k] = (mm && mask_bound) ? 1.0f : 0.0f;
    }
}

extern "C" void kernel_launch(void* const* d_in, const int* in_sizes, int n_in,
                              void* d_out, int out_size, void* d_ws, size_t ws_size,
                              hipStream_t stream) {
    const float* rays_o = (const float*)d_in[0];
    const float* rays_d = (const float*)d_in[1];
    const float* levels = (const float*)d_in[2];
    const float* W1 = (const float*)d_in[3];
    const float* b1 = (const float*)d_in[4];
    const float* W2 = (const float*)d_in[5];
    const float* b2 = (const float*)d_in[6];
    float* out = (float*)d_out;

    const int N = in_sizes[0] / 3;          // B*R rays
    const int blocks = (N + 3) / 4;         // 4 waves (rays) per 256-thread block
    manifold_render_kernel<<<blocks, 256, 0, stream>>>(
        rays_o, rays_d, levels, W1, b1, W2, b2, out, N);
}